// Round 1
// baseline (261.714 us; speedup 1.0000x reference)
//
#include <hip/hip_runtime.h>
#include <math.h>

#define B_    8
#define R_    400
#define N_    1200
#define S_    5
#define LMAX_ 544
#define NPSI_ 1024
#define KPAD  560      // LMAX rounded up to multiple of T_, zero-padded
#define WINMAX 1760    // max staged g-window: 1199 + KPAD + 1
#define T_    20       // outputs per lane

// ---------------- ws layout (floats) ----------------
// [0, 1024)                    INT_PSI (f32, cast from f64 cumsum)
// [1024, 1024+40*KPAD)         K baked per (b,s) pair, zero-padded to KPAD
// then: scale[40], sqs[40], L[40](int), start[40](int)
#define WS_K      1024
#define WS_SCALE  (WS_K + 40*KPAD)
#define WS_SQS    (WS_SCALE + 40)
#define WS_L      (WS_SQS + 40)
#define WS_START  (WS_L + 40)

__global__ void setup_kernel(const float* __restrict__ tr,
                             const float* __restrict__ lsp,
                             const float* __restrict__ bwp,
                             float* __restrict__ ws,
                             float* __restrict__ out_bands)
{
    __shared__ double psi_sh[NPSI_];
    const double STEP_D = 16.0 / 1023.0;
    const float  STEP_F = (float)(16.0 / 1023.0);
    const int tid = threadIdx.x;

    // psi in f64 (mirrors numpy: linspace endpoint pinned to 8.0)
    for (int k = tid; k < NPSI_; k += 256) {
        double x = (k == NPSI_ - 1) ? 8.0 : (-8.0 + (double)k * STEP_D);
        psi_sh[k] = exp(-x * x * 0.5) * cos(5.0 * x);
    }
    __syncthreads();

    // sequential f64 cumsum (exact np.cumsum association), *STEP, cast f32
    if (tid == 0) {
        double c = 0.0;
        for (int k = 0; k < NPSI_; ++k) {
            c += psi_sh[k];
            ws[k] = (float)(c * STEP_D);
        }
    }
    __syncthreads();

    float* scale_arr = ws + WS_SCALE;
    float* sqs_arr   = ws + WS_SQS;
    int*   L_arr     = (int*)(ws + WS_L);
    int*   start_arr = (int*)(ws + WS_START);

    if (tid < 40) {
        int b = tid / S_, s = tid % S_;
        float trf   = tr[b] / 2.0f;                  // tr_values / REF_TR
        float scale = expf(lsp[s]) / trf;            // f32 throughout, like XLA
        float sst   = scale * STEP_F;
        int   L0    = (int)floorf(scale * 16.0f) + 2;
        int   L     = 0;
        for (int i = 0; i < LMAX_; ++i) {
            int j = (int)floorf((float)i / sst);
            if (i < L0 && j < NPSI_) ++L;
        }
        scale_arr[tid] = scale;
        sqs_arr[tid]   = sqrtf(scale);
        L_arr[tid]     = L;
        start_arr[tid] = LMAX_ + (L - 2) / 2 + 2 - L;   // L>=2 so C trunc == floor

        // frequency bands -> tail of d_out
        float center = 1.0f / (scale * tr[b]);
        float bw     = bwp[s];
        float lo = fmaxf(0.008f, center * (1.0f - bw / 2.0f));
        float hi = fminf(0.12f,  center * (1.0f + bw / 2.0f));
        out_bands[tid * 2 + 0] = lo;
        out_bands[tid * 2 + 1] = hi;
    }
    __syncthreads();

    // bake K[pair][KPAD], zero-padded
    for (int idx = tid; idx < 40 * KPAD; idx += 256) {
        int p = idx / KPAD;
        int i = idx % KPAD;
        float v = 0.0f;
        if (i < LMAX_) {
            float scale = scale_arr[p];
            float sst   = scale * STEP_F;
            int   L0    = (int)floorf(scale * 16.0f) + 2;
            int   j     = (int)floorf((float)i / sst);
            if (i < L0 && j < NPSI_) {
                int jc = j < 0 ? 0 : (j > NPSI_ - 1 ? NPSI_ - 1 : j);
                v = ws[jc];   // INT_PSI f32
            }
        }
        ws[WS_K + idx] = v;
    }
}

__global__ __launch_bounds__(256) void cwt_main_kernel(
    const float* __restrict__ ts,
    const float* __restrict__ ws,
    float* __restrict__ out)
{
    const float* Kbase     = ws + WS_K;
    const float* sqs_arr   = ws + WS_SQS;
    const int*   L_arr     = (const int*)(ws + WS_L);
    const int*   start_arr = (const int*)(ws + WS_START);

    // bid -> (s descending for load balance, b, row-group)
    const int bid = blockIdx.x;
    const int rg  = bid % 100;            // 100 groups of 4 rows
    const int b   = (bid / 100) % B_;
    const int s   = 4 - (bid / (100 * B_));   // heavy scales dispatched first
    const int pair = b * S_ + s;

    const int   L      = L_arr[pair];
    const int   start  = start_arr[pair];
    const float sqs    = sqs_arr[pair];
    const int   wstart = start - LMAX_;            // g-index of gwin[.][0]
    const int   Lpad   = ((L + T_ - 1) / T_) * T_; // <= KPAD, zero-K tail

    __shared__ __align__(16) float gwin[4][WINMAX];

    const int tid = threadIdx.x;

    // stage 4 rows: g computed on the fly from ts (g = diff of zero-extended)
    for (int wv = 0; wv < 4; ++wv) {
        const int r = rg * 4 + wv;
        const float* tsrow = ts + (size_t)(b * R_ + r) * N_;
        for (int t = tid; t < WINMAX; t += 256) {
            int k = wstart + t;
            float v = 0.0f;
            if (k >= 0 && k <= N_) {
                float a = (k < N_) ? tsrow[k]     : 0.0f;
                float c = (k > 0)  ? tsrow[k - 1] : 0.0f;
                v = a - c;
            }
            gwin[wv][t] = v;
        }
    }
    __syncthreads();

    const int wv = tid >> 6;
    const int ln = tid & 63;
    const int t0 = T_ * (ln < 60 ? ln : 59);   // lanes 60..63 duplicate lane 59
    const float* gw = gwin[wv];
    const float* Kp = Kbase + pair * KPAD;     // uniform -> s_load

    float acc[T_];
    #pragma unroll
    for (int q = 0; q < T_; ++q) acc[q] = 0.0f;

    for (int i = 0; i < Lpad; i += T_) {
        float kk[T_];
        #pragma unroll
        for (int m = 0; m < T_ / 4; ++m)
            *(float4*)&kk[4 * m] = *(const float4*)(Kp + i + 4 * m);

        float w[2 * T_];
        #pragma unroll
        for (int m = 0; m < 2 * T_ / 4; ++m)
            *(float4*)&w[4 * m] = *(const float4*)(gw + t0 + i + 4 * m);

        #pragma unroll
        for (int q = 0; q < T_; ++q) {
            #pragma unroll
            for (int j = 0; j < T_; ++j)
                acc[q] = fmaf(kk[j], w[q + j], acc[q]);
        }
    }

    if (ln < 60) {
        const int r = rg * 4 + wv;
        float* op = out + ((size_t)(b * R_ + r) * S_ + s) * N_ + t0;
        #pragma unroll
        for (int m = 0; m < T_ / 4; ++m) {
            float4 v;
            v.x = sqs * fabsf(acc[4 * m + 0]);
            v.y = sqs * fabsf(acc[4 * m + 1]);
            v.z = sqs * fabsf(acc[4 * m + 2]);
            v.w = sqs * fabsf(acc[4 * m + 3]);
            *(float4*)(op + 4 * m) = v;
        }
    }
}

extern "C" void kernel_launch(void* const* d_in, const int* in_sizes, int n_in,
                              void* d_out, int out_size, void* d_ws, size_t ws_size,
                              hipStream_t stream)
{
    const float* ts  = (const float*)d_in[0];
    const float* tr  = (const float*)d_in[1];
    const float* lsp = (const float*)d_in[2];
    const float* bwp = (const float*)d_in[3];
    float* out = (float*)d_out;
    float* ws  = (float*)d_ws;
    float* out_bands = out + (size_t)B_ * R_ * S_ * N_;   // coeffs first, bands after

    hipLaunchKernelGGL(setup_kernel, dim3(1), dim3(256), 0, stream,
                       tr, lsp, bwp, ws, out_bands);
    hipLaunchKernelGGL(cwt_main_kernel, dim3(100 * B_ * S_), dim3(256), 0, stream,
                       ts, ws, out);
}

// Round 2
// 238.746 us; speedup vs baseline: 1.0962x; 1.0962x over previous
//
#include <hip/hip_runtime.h>
#include <math.h>

#define B_    8
#define R_    400
#define N_    1200
#define S_    5
#define LMAX_ 544
#define NPSI_ 1024
#define KPAD  560      // LMAX rounded up, zero-padded (multiple of 8; >= max Lpad 552)
#define WINMAX 1760    // staged g-window dwords per row (>= 1180+552+19+1, mult of 32)
#define T_    20       // outputs per lane

// ---------------- ws layout (floats) ----------------
#define WS_K      0
#define WS_SCALE  (40*KPAD)
#define WS_SQS    (WS_SCALE + 40)
#define WS_L      (WS_SQS + 40)
#define WS_START  (WS_L + 40)

// granule-level XOR swizzle: bijective (involution), keeps 16B chunks contiguous.
// lane granule = C + 5*lane; (G%8)^((G>>3)&7) is balanced over all 64 residues
// -> exactly 8 accesses per bank per b128 wave-read = conflict-free minimum.
__device__ __forceinline__ float4 lds_ld4(const float* base, int dw) {
    int g = dw >> 2;
    g ^= (g >> 3) & 7;
    return *(const float4*)(base + (g << 2));
}

__global__ __launch_bounds__(256) void setup_kernel(
    const float* __restrict__ tr,
    const float* __restrict__ lsp,
    const float* __restrict__ bwp,
    float* __restrict__ ws,
    float* __restrict__ out_bands)
{
    __shared__ double psi_sh[NPSI_];
    __shared__ float  intpsi[NPSI_];
    __shared__ double wtot[4];
    __shared__ float  scale_sh[40];
    __shared__ int    cnt_sh[40];
    const double STEP_D = 16.0 / 1023.0;
    const float  STEP_F = (float)(16.0 / 1023.0);
    const int tid = threadIdx.x;

    if (tid < 40) cnt_sh[tid] = 0;

    // psi in f64 (numpy linspace endpoint pinned to 8.0)
    for (int k = tid; k < NPSI_; k += 256) {
        double x = (k == NPSI_ - 1) ? 8.0 : (-8.0 + (double)k * STEP_D);
        psi_sh[k] = exp(-x * x * 0.5) * cos(5.0 * x);
    }
    __syncthreads();

    // parallel f64 cumsum: 4 elems/thread + wave scan + cross-wave offsets.
    // association differs from np.cumsum only at f64 precision -> invisible in f32.
    {
        double a0 = psi_sh[4 * tid + 0], a1 = psi_sh[4 * tid + 1];
        double a2 = psi_sh[4 * tid + 2], a3 = psi_sh[4 * tid + 3];
        double s1 = a0 + a1, s2 = s1 + a2, s3 = s2 + a3;
        double run = s3;
        #pragma unroll
        for (int d = 1; d < 64; d <<= 1) {
            double o = __shfl_up(run, (unsigned)d, 64);
            if ((tid & 63) >= d) run += o;
        }
        if ((tid & 63) == 63) wtot[tid >> 6] = run;
        __syncthreads();
        double woff = 0.0;
        const int w = tid >> 6;
        #pragma unroll
        for (int k = 0; k < 4; ++k) if (k < w) woff += wtot[k];
        double excl = woff + run - s3;
        intpsi[4 * tid + 0] = (float)((excl + a0) * STEP_D);
        intpsi[4 * tid + 1] = (float)((excl + s1) * STEP_D);
        intpsi[4 * tid + 2] = (float)((excl + s2) * STEP_D);
        intpsi[4 * tid + 3] = (float)((excl + s3) * STEP_D);
    }

    if (tid < 40) {
        int b = tid / S_, s = tid % S_;
        float trf   = tr[b] / 2.0f;
        float scale = expf(lsp[s]) / trf;          // f32 ops matching XLA
        scale_sh[tid] = scale;
        ws[WS_SCALE + tid] = scale;
        ws[WS_SQS + tid]   = sqrtf(scale);
        float center = 1.0f / (scale * tr[b]);
        float bw = bwp[s];
        out_bands[2 * tid + 0] = fmaxf(0.008f, center * (1.0f - bw * 0.5f));
        out_bands[2 * tid + 1] = fminf(0.12f,  center * (1.0f + bw * 0.5f));
    }
    __syncthreads();

    // L count: 40 pairs x 9 chunks of 64 i's, ballot+popcount, one LDS atomic/chunk
    {
        const int wv = tid >> 6, ln = tid & 63;
        for (int c = wv; c < 40 * 9; c += 4) {
            int p = c / 9, i = (c % 9) * 64 + ln;
            float scale = scale_sh[p];
            float sst   = scale * STEP_F;
            int   L0    = (int)floorf(scale * 16.0f) + 2;
            bool m = false;
            if (i < LMAX_) {
                int j = (int)floorf((float)i / sst);   // IEEE f32 div (matches ref)
                m = (i < L0) && (j < NPSI_);
            }
            unsigned long long bal = __ballot(m);
            if (ln == 0) atomicAdd(&cnt_sh[p], __popcll(bal));
        }
    }
    __syncthreads();
    if (tid < 40) {
        int L = cnt_sh[tid];
        ((int*)(ws + WS_L))[tid]     = L;
        ((int*)(ws + WS_START))[tid] = LMAX_ + (L - 2) / 2 + 2 - L;
    }

    // bake K[pair][KPAD], zero-padded
    for (int idx = tid; idx < 40 * KPAD; idx += 256) {
        int p = idx / KPAD, i = idx % KPAD;
        float v = 0.0f;
        if (i < LMAX_) {
            float scale = scale_sh[p];
            float sst   = scale * STEP_F;
            int   L0    = (int)floorf(scale * 16.0f) + 2;
            int   j     = (int)floorf((float)i / sst);
            if (i < L0 && j < NPSI_) {
                int jc = j < 0 ? 0 : (j > NPSI_ - 1 ? NPSI_ - 1 : j);
                v = intpsi[jc];
            }
        }
        ws[WS_K + idx] = v;
    }
}

__global__ __launch_bounds__(256) void cwt_main_kernel(
    const float* __restrict__ ts,
    const float* __restrict__ ws,
    float* __restrict__ out)
{
    const float* Kbase     = ws + WS_K;
    const float* sqs_arr   = ws + WS_SQS;
    const int*   L_arr     = (const int*)(ws + WS_L);
    const int*   start_arr = (const int*)(ws + WS_START);

    const int bid = blockIdx.x;
    const int rg  = bid % 100;
    const int b   = (bid / 100) % B_;
    const int s   = 4 - (bid / (100 * B_));   // heavy scales first
    const int pair = b * S_ + s;

    const int   L      = L_arr[pair];
    const int   start  = start_arr[pair];
    const float sqs    = sqs_arr[pair];
    const int   wstart = start - LMAX_;
    const int   Lpad   = ((L + 23) / 24) * 24;   // <= 552 < KPAD, zero-K tail

    __shared__ __align__(16) float gwin[4 * WINMAX];

    const int tid = threadIdx.x;

    // stage 4 rows of g (diff of zero-extended signal), swizzled writes
    for (int wv = 0; wv < 4; ++wv) {
        const int r = rg * 4 + wv;
        const float* tsrow = ts + (size_t)(b * R_ + r) * N_;
        for (int t = tid; t < WINMAX; t += 256) {
            int k = wstart + t;
            float v = 0.0f;
            if (k >= 0 && k <= N_) {
                float a = (k < N_) ? tsrow[k]     : 0.0f;
                float c = (k > 0)  ? tsrow[k - 1] : 0.0f;
                v = a - c;
            }
            int dw = wv * WINMAX + t;
            int g  = dw >> 2;
            g ^= (g >> 3) & 7;
            gwin[(g << 2) | (dw & 3)] = v;
        }
    }
    __syncthreads();

    const int wv = tid >> 6;
    const int ln = tid & 63;
    const int t0 = T_ * (ln < 60 ? ln : 59);   // lanes 60..63 duplicate lane 59
    const int dwbase = wv * WINMAX + t0;
    const float* Kp = Kbase + pair * KPAD;     // uniform -> s_load

    float acc[T_];
    #pragma unroll
    for (int q = 0; q < T_; ++q) acc[q] = 0.0f;

    // rolling 24-dword register window: W[l % 24] = w[t0 + l]
    float W[24];
    #pragma unroll
    for (int m = 0; m < 5; ++m)
        *(float4*)&W[4 * m] = lds_ld4(gwin, dwbase + 4 * m);

    for (int i = 0; i < Lpad; i += 24) {
        #pragma unroll
        for (int p = 0; p < 6; ++p) {
            const int slot = (4 * p + 20) % 24;         // 20,0,4,8,12,16
            *(float4*)&W[slot] = lds_ld4(gwin, dwbase + i + 4 * p + 20);
            float4 k4 = *(const float4*)(Kp + i + 4 * p);
            #pragma unroll
            for (int j = 0; j < 4; ++j) {
                const float kv = (j == 0) ? k4.x : (j == 1) ? k4.y : (j == 2) ? k4.z : k4.w;
                #pragma unroll
                for (int q = 0; q < T_; ++q)
                    acc[q] = fmaf(kv, W[(4 * p + j + q) % 24], acc[q]);
            }
        }
    }

    if (ln < 60) {
        const int r = rg * 4 + wv;
        float* op = out + ((size_t)(b * R_ + r) * S_ + s) * N_ + t0;
        #pragma unroll
        for (int m = 0; m < T_ / 4; ++m) {
            float4 v;
            v.x = sqs * fabsf(acc[4 * m + 0]);
            v.y = sqs * fabsf(acc[4 * m + 1]);
            v.z = sqs * fabsf(acc[4 * m + 2]);
            v.w = sqs * fabsf(acc[4 * m + 3]);
            *(float4*)(op + 4 * m) = v;
        }
    }
}

extern "C" void kernel_launch(void* const* d_in, const int* in_sizes, int n_in,
                              void* d_out, int out_size, void* d_ws, size_t ws_size,
                              hipStream_t stream)
{
    const float* ts  = (const float*)d_in[0];
    const float* tr  = (const float*)d_in[1];
    const float* lsp = (const float*)d_in[2];
    const float* bwp = (const float*)d_in[3];
    float* out = (float*)d_out;
    float* ws  = (float*)d_ws;
    float* out_bands = out + (size_t)B_ * R_ * S_ * N_;

    hipLaunchKernelGGL(setup_kernel, dim3(1), dim3(256), 0, stream,
                       tr, lsp, bwp, ws, out_bands);
    hipLaunchKernelGGL(cwt_main_kernel, dim3(100 * B_ * S_), dim3(256), 0, stream,
                       ts, ws, out);
}

// Round 4
// 225.104 us; speedup vs baseline: 1.1626x; 1.0606x over previous
//
#include <hip/hip_runtime.h>
#include <math.h>

#define B_    8
#define R_    400
#define N_    1200
#define S_    5
#define LMAX_ 544
#define NPSI_ 1024
#define KPAD  560      // >= max Lpad (552), zero-padded
#define WINMAX 1792    // staged g-window per row: 1197 + 552 + 23 = 1772 -> 1792
#define T_    19       // outputs per lane; ODD -> ds_read_b32 lane stride 19 dwords
                       // -> gcd(19,32)=1 -> 2 lanes/bank = conflict-free (m136)
#define C_    24       // taps per unrolled outer iteration (W slots cycle exactly once)
#define WSZ   24       // rolling window registers

// ---------------- ws layout (floats) ----------------
#define WS_K      0
#define WS_SCALE  (40*KPAD)
#define WS_SQS    (WS_SCALE + 40)
#define WS_LPAD   (WS_SQS + 40)
#define WS_WST    (WS_LPAD + 40)

__global__ __launch_bounds__(256) void setup_kernel(
    const float* __restrict__ tr,
    const float* __restrict__ lsp,
    const float* __restrict__ bwp,
    float* __restrict__ ws,
    float* __restrict__ out_bands)
{
    __shared__ double psi_sh[NPSI_];
    __shared__ float  intpsi[NPSI_];
    __shared__ double wtot[4];
    __shared__ float  scale_sh[40];
    __shared__ int    cnt_sh[40];
    const double STEP_D = 16.0 / 1023.0;
    const float  STEP_F = (float)(16.0 / 1023.0);
    const int tid = threadIdx.x;

    if (tid < 40) cnt_sh[tid] = 0;

    // psi in f64 (numpy linspace endpoint pinned to 8.0)
    for (int k = tid; k < NPSI_; k += 256) {
        double x = (k == NPSI_ - 1) ? 8.0 : (-8.0 + (double)k * STEP_D);
        psi_sh[k] = exp(-x * x * 0.5) * cos(5.0 * x);
    }
    __syncthreads();

    // parallel f64 cumsum (association change invisible after f32 cast)
    {
        double a0 = psi_sh[4 * tid + 0], a1 = psi_sh[4 * tid + 1];
        double a2 = psi_sh[4 * tid + 2], a3 = psi_sh[4 * tid + 3];
        double s1 = a0 + a1, s2 = s1 + a2, s3 = s2 + a3;
        double run = s3;
        #pragma unroll
        for (int d = 1; d < 64; d <<= 1) {
            double o = __shfl_up(run, (unsigned)d, 64);
            if ((tid & 63) >= d) run += o;
        }
        if ((tid & 63) == 63) wtot[tid >> 6] = run;
        __syncthreads();
        double woff = 0.0;
        const int w = tid >> 6;
        #pragma unroll
        for (int k = 0; k < 4; ++k) if (k < w) woff += wtot[k];
        double excl = woff + run - s3;
        intpsi[4 * tid + 0] = (float)((excl + a0) * STEP_D);
        intpsi[4 * tid + 1] = (float)((excl + s1) * STEP_D);
        intpsi[4 * tid + 2] = (float)((excl + s2) * STEP_D);
        intpsi[4 * tid + 3] = (float)((excl + s3) * STEP_D);
    }

    if (tid < 40) {
        int b = tid / S_, s = tid % S_;
        float trf   = tr[b] / 2.0f;
        float scale = expf(lsp[s]) / trf;          // f32 ops matching XLA
        scale_sh[tid] = scale;
        ws[WS_SQS + tid] = sqrtf(scale);
        float center = 1.0f / (scale * tr[b]);
        float bw = bwp[s];
        out_bands[2 * tid + 0] = fmaxf(0.008f, center * (1.0f - bw * 0.5f));
        out_bands[2 * tid + 1] = fminf(0.12f,  center * (1.0f + bw * 0.5f));
    }
    __syncthreads();

    // L count: ballot+popcount over 40 pairs x 9 chunks of 64
    {
        const int wv = tid >> 6, ln = tid & 63;
        for (int c = wv; c < 40 * 9; c += 4) {
            int p = c / 9, i = (c % 9) * 64 + ln;
            float scale = scale_sh[p];
            float sst   = scale * STEP_F;
            int   L0    = (int)floorf(scale * 16.0f) + 2;
            bool m = false;
            if (i < LMAX_) {
                int j = (int)floorf((float)i / sst);   // IEEE f32 div (matches ref)
                m = (i < L0) && (j < NPSI_);
            }
            unsigned long long bal = __ballot(m);
            if (ln == 0) atomicAdd(&cnt_sh[p], __popcll(bal));
        }
    }
    __syncthreads();
    if (tid < 40) {
        int L = cnt_sh[tid];
        ((int*)(ws + WS_LPAD))[tid] = ((L + C_ - 1) / C_) * C_;     // <= 552
        ((int*)(ws + WS_WST))[tid]  = (L - 2) / 2 + 2 - L;          // wstart (g-index)
    }

    // bake K[pair][KPAD], zero-padded
    for (int idx = tid; idx < 40 * KPAD; idx += 256) {
        int p = idx / KPAD, i = idx % KPAD;
        float v = 0.0f;
        if (i < LMAX_) {
            float scale = scale_sh[p];
            float sst   = scale * STEP_F;
            int   L0    = (int)floorf(scale * 16.0f) + 2;
            int   j     = (int)floorf((float)i / sst);
            if (i < L0 && j < NPSI_) {
                int jc = j < 0 ? 0 : (j > NPSI_ - 1 ? NPSI_ - 1 : j);
                v = intpsi[jc];
            }
        }
        ws[WS_K + idx] = v;
    }
}

__global__ __launch_bounds__(128) void cwt_main_kernel(
    const float* __restrict__ ts,
    const float* __restrict__ ws,
    float* __restrict__ out)
{
    const float* __restrict__ Kbase = ws + WS_K;
    const float* sqs_arr  = ws + WS_SQS;
    const int*   Lpad_arr = (const int*)(ws + WS_LPAD);
    const int*   wst_arr  = (const int*)(ws + WS_WST);

    // grid 8000: s descending (heavy first), b, row-pair
    const int bid = blockIdx.x;
    const int s   = 4 - bid / 1600;
    const int rem = bid % 1600;
    const int b   = rem / 200;
    const int rp  = rem % 200;
    const int pair = b * S_ + s;

    const int   Lpad   = Lpad_arr[pair];
    const int   wstart = wst_arr[pair];
    const float sqs    = sqs_arr[pair];

    __shared__ float gwin[2][WINMAX];
    const int tid = threadIdx.x;

    // stage 2 rows of g (diff of zero-extended signal), plain layout
    for (int rr = 0; rr < 2; ++rr) {
        const float* tsrow = ts + (size_t)(b * R_ + rp * 2 + rr) * N_;
        for (int t = tid; t < WINMAX; t += 128) {
            int k = wstart + t;
            float v = 0.0f;
            if (k >= 0 && k <= N_) {
                float a = (k < N_) ? tsrow[k]     : 0.0f;
                float c = (k > 0)  ? tsrow[k - 1] : 0.0f;
                v = a - c;
            }
            gwin[rr][t] = v;
        }
    }
    __syncthreads();

    const int wv = tid >> 6;
    const int ln = tid & 63;
    const int t0 = T_ * ln;                 // 0..1197, odd lane stride
    const float* gw = &gwin[wv][0];
    const float* __restrict__ Kp = Kbase + pair * KPAD;   // uniform -> s_load

    float acc[T_];
    #pragma unroll
    for (int q = 0; q < T_; ++q) acc[q] = 0.0f;

    // rolling register window: at top of iter i, W[m] == gw[t0 + i + m]
    float W[WSZ];
    #pragma unroll
    for (int x = 0; x < WSZ; ++x) W[x] = gw[t0 + x];

    for (int i = 0; i < Lpad; i += C_) {
        #pragma unroll
        for (int u = 0; u < C_; ++u) {
            const float kv = Kp[i + u];        // scalar (SGPR) operand
            #pragma unroll
            for (int q = 0; q < T_; ++q)
                acc[q] = fmaf(kv, W[(u + q) % WSZ], acc[q]);
            W[u] = gw[t0 + i + u + WSZ];       // refill freed slot (b32, imm offset)
        }
    }

    // store 19 outputs (lane 63 partially masked)
    {
        const int r = rp * 2 + wv;
        float* op = out + ((size_t)(b * R_ + r) * S_ + s) * N_;
        #pragma unroll
        for (int q = 0; q < T_; ++q) {
            int t = t0 + q;
            if (t < N_) op[t] = sqs * fabsf(acc[q]);
        }
    }
}

extern "C" void kernel_launch(void* const* d_in, const int* in_sizes, int n_in,
                              void* d_out, int out_size, void* d_ws, size_t ws_size,
                              hipStream_t stream)
{
    const float* ts  = (const float*)d_in[0];
    const float* tr  = (const float*)d_in[1];
    const float* lsp = (const float*)d_in[2];
    const float* bwp = (const float*)d_in[3];
    float* out = (float*)d_out;
    float* ws  = (float*)d_ws;
    float* out_bands = out + (size_t)B_ * R_ * S_ * N_;

    hipLaunchKernelGGL(setup_kernel, dim3(1), dim3(256), 0, stream,
                       tr, lsp, bwp, ws, out_bands);
    hipLaunchKernelGGL(cwt_main_kernel, dim3(8000), dim3(128), 0, stream,
                       ts, ws, out);
}

// Round 6
// 211.768 us; speedup vs baseline: 1.2359x; 1.0630x over previous
//
#include <hip/hip_runtime.h>
#include <math.h>

#define B_    8
#define R_    400
#define N_    1200
#define S_    5
#define LMAX_ 544
#define NPSI_ 1024
#define KPAD  576      // >= max Lpad (576), multiple of C_
#define KLDS  640      // K_lds size: KPAD + C_ prefetch overrun headroom
#define WINMAX 1824    // >= 1197 + Lpad_max(576) + 23 = 1796
#define T_    19       // outputs/lane; ODD dword stride -> conflict-free b32 (r4: verified 0)
#define C_    48       // outer tap step (two 24-halves, double-buffered K)
#define WSZ   24       // rolling window registers

// ---------------- ws layout (floats) ----------------
#define WS_K      0
#define WS_SCALE  (40*KPAD)
#define WS_SQS    (WS_SCALE + 40)
#define WS_LPAD   (WS_SQS + 40)
#define WS_WST    (WS_LPAD + 40)
#define WS_INTPSI (WS_WST + 40)

// ---------- setup A: psi + f64 scan + per-pair scalars (1 block) ----------
__global__ __launch_bounds__(256) void setup_a_kernel(
    const float* __restrict__ tr,
    const float* __restrict__ lsp,
    const float* __restrict__ bwp,
    float* __restrict__ ws,
    float* __restrict__ out_bands)
{
    __shared__ double psi_sh[NPSI_];
    __shared__ double wtot[4];
    const double STEP_D = 16.0 / 1023.0;
    const int tid = threadIdx.x;

    for (int k = tid; k < NPSI_; k += 256) {
        double x = (k == NPSI_ - 1) ? 8.0 : (-8.0 + (double)k * STEP_D);
        psi_sh[k] = exp(-x * x * 0.5) * cos(5.0 * x);
    }
    __syncthreads();

    // parallel f64 cumsum (association change invisible after f32 cast)
    {
        double a0 = psi_sh[4 * tid + 0], a1 = psi_sh[4 * tid + 1];
        double a2 = psi_sh[4 * tid + 2], a3 = psi_sh[4 * tid + 3];
        double s1 = a0 + a1, s2 = s1 + a2, s3 = s2 + a3;
        double run = s3;
        #pragma unroll
        for (int d = 1; d < 64; d <<= 1) {
            double o = __shfl_up(run, (unsigned)d, 64);
            if ((tid & 63) >= d) run += o;
        }
        if ((tid & 63) == 63) wtot[tid >> 6] = run;
        __syncthreads();
        double woff = 0.0;
        const int w = tid >> 6;
        #pragma unroll
        for (int k = 0; k < 4; ++k) if (k < w) woff += wtot[k];
        double excl = woff + run - s3;
        ws[WS_INTPSI + 4 * tid + 0] = (float)((excl + a0) * STEP_D);
        ws[WS_INTPSI + 4 * tid + 1] = (float)((excl + s1) * STEP_D);
        ws[WS_INTPSI + 4 * tid + 2] = (float)((excl + s2) * STEP_D);
        ws[WS_INTPSI + 4 * tid + 3] = (float)((excl + s3) * STEP_D);
    }

    if (tid < 40) {
        int b = tid / S_, s = tid % S_;
        float trf   = tr[b] / 2.0f;
        float scale = expf(lsp[s]) / trf;          // f32 ops matching XLA
        ws[WS_SCALE + tid] = scale;
        ws[WS_SQS + tid]   = sqrtf(scale);
        float center = 1.0f / (scale * tr[b]);
        float bw = bwp[s];
        out_bands[2 * tid + 0] = fmaxf(0.008f, center * (1.0f - bw * 0.5f));
        out_bands[2 * tid + 1] = fminf(0.12f,  center * (1.0f + bw * 0.5f));
    }
}

// ---------- setup B: per-pair L-count + K bake (40 blocks) ----------
__global__ __launch_bounds__(256) void setup_b_kernel(float* __restrict__ ws)
{
    const int p   = blockIdx.x;
    const int tid = threadIdx.x;
    const float STEP_F = (float)(16.0 / 1023.0);

    const float scale = ws[WS_SCALE + p];
    const float sst   = scale * STEP_F;
    const int   L0    = (int)floorf(scale * 16.0f) + 2;

    __shared__ int cnt;
    if (tid == 0) cnt = 0;
    __syncthreads();

    const int ln = tid & 63;
    for (int base = 0; base < LMAX_; base += 256) {
        int i = base + tid;
        bool m = false;
        if (i < LMAX_) {
            int j = (int)floorf((float)i / sst);   // IEEE f32 div (matches ref)
            m = (i < L0) && (j < NPSI_);
        }
        unsigned long long bal = __ballot(m);
        if (ln == 0) atomicAdd(&cnt, __popcll(bal));
    }

    // K bake for this pair
    for (int i = tid; i < KPAD; i += 256) {
        float v = 0.0f;
        if (i < LMAX_) {
            int j = (int)floorf((float)i / sst);
            if (i < L0 && j < NPSI_) {
                int jc = j < 0 ? 0 : (j > NPSI_ - 1 ? NPSI_ - 1 : j);
                v = ws[WS_INTPSI + jc];
            }
        }
        ws[WS_K + p * KPAD + i] = v;
    }
    __syncthreads();

    if (tid == 0) {
        int L = cnt;
        ((int*)(ws + WS_LPAD))[p] = ((L + C_ - 1) / C_) * C_;   // <= 576
        ((int*)(ws + WS_WST))[p]  = (L - 2) / 2 + 2 - L;        // wstart g-index
    }
}

// ---------- main CWT kernel ----------
__global__ __launch_bounds__(128) void cwt_main_kernel(
    const float* __restrict__ ts,
    const float* __restrict__ ws,
    float* __restrict__ out)
{
    const float* __restrict__ Kbase = ws + WS_K;
    const float* sqs_arr  = ws + WS_SQS;
    const int*   Lpad_arr = (const int*)(ws + WS_LPAD);
    const int*   wst_arr  = (const int*)(ws + WS_WST);

    // grid 8000: s descending (heavy first), b, row-pair
    const int bid = blockIdx.x;
    const int s   = 4 - bid / 1600;
    const int rem = bid % 1600;
    const int b   = rem / 200;
    const int rp  = rem % 200;
    const int pair = b * S_ + s;

    const int   Lpad   = Lpad_arr[pair];
    const int   wstart = wst_arr[pair];
    const float sqs    = sqs_arr[pair];

    __shared__ float gwin[2][WINMAX];
    __shared__ __align__(16) float K_lds[KLDS];
    const int tid = threadIdx.x;

    // stage K (DS-homogeneous inner loop: no SMEM in flight during FMAs)
    {
        const float* __restrict__ Kp = Kbase + pair * KPAD;
        for (int t = tid; t < KLDS; t += 128)
            K_lds[t] = (t < KPAD) ? Kp[t] : 0.0f;
    }

    // stage 2 rows of g (diff of zero-extended signal), plain layout
    for (int rr = 0; rr < 2; ++rr) {
        const float* tsrow = ts + (size_t)(b * R_ + rp * 2 + rr) * N_;
        for (int t = tid; t < WINMAX; t += 128) {
            int k = wstart + t;
            float v = 0.0f;
            if (k >= 0 && k <= N_) {
                float a = (k < N_) ? tsrow[k]     : 0.0f;
                float c = (k > 0)  ? tsrow[k - 1] : 0.0f;
                v = a - c;
            }
            gwin[rr][t] = v;
        }
    }
    __syncthreads();

    const int wv = tid >> 6;
    const int ln = tid & 63;
    const int t0 = T_ * ln;                 // 0..1197, odd lane stride
    const float* gw = &gwin[wv][0];

    float acc[T_];
    #pragma unroll
    for (int q = 0; q < T_; ++q) acc[q] = 0.0f;

    // rolling register window: at sub-tap m of outer iter i, W[(m+q)%24] == gw[t0+i+m+q]
    float W[WSZ];
    #pragma unroll
    for (int x = 0; x < WSZ; ++x) W[x] = gw[t0 + x];

    // K double-buffer: broadcast ds_read_b128 (uniform addr -> conflict-free)
    float kva[24], kvb[24];
    #pragma unroll
    for (int m = 0; m < 6; ++m)
        *(float4*)&kva[4 * m] = *(const float4*)&K_lds[4 * m];          // taps 0..23

    for (int i = 0; i < Lpad; i += C_) {
        // prefetch half B: taps i+24..i+47
        #pragma unroll
        for (int m = 0; m < 6; ++m)
            *(float4*)&kvb[4 * m] = *(const float4*)&K_lds[i + 24 + 4 * m];
        #pragma unroll
        for (int u = 0; u < 24; ++u) {
            #pragma unroll
            for (int q = 0; q < T_; ++q)
                acc[q] = fmaf(kva[u], W[(u + q) % WSZ], acc[q]);
            W[u] = gw[t0 + i + u + WSZ];
        }
        // prefetch half A for next outer iter: taps i+48..i+71 (<= K_lds[623], zero/garbage-safe pad)
        #pragma unroll
        for (int m = 0; m < 6; ++m)
            *(float4*)&kva[4 * m] = *(const float4*)&K_lds[i + 48 + 4 * m];
        #pragma unroll
        for (int u = 0; u < 24; ++u) {
            #pragma unroll
            for (int q = 0; q < T_; ++q)
                acc[q] = fmaf(kvb[u], W[(u + q) % WSZ], acc[q]);
            W[u] = gw[t0 + i + u + 48];
        }
    }

    // store 19 outputs (lane 63 partially masked)
    {
        const int r = rp * 2 + wv;
        float* op = out + ((size_t)(b * R_ + r) * S_ + s) * N_;
        #pragma unroll
        for (int q = 0; q < T_; ++q) {
            int t = t0 + q;
            if (t < N_) op[t] = sqs * fabsf(acc[q]);
        }
    }
}

extern "C" void kernel_launch(void* const* d_in, const int* in_sizes, int n_in,
                              void* d_out, int out_size, void* d_ws, size_t ws_size,
                              hipStream_t stream)
{
    const float* ts  = (const float*)d_in[0];
    const float* tr  = (const float*)d_in[1];
    const float* lsp = (const float*)d_in[2];
    const float* bwp = (const float*)d_in[3];
    float* out = (float*)d_out;
    float* ws  = (float*)d_ws;
    float* out_bands = out + (size_t)B_ * R_ * S_ * N_;

    hipLaunchKernelGGL(setup_a_kernel, dim3(1), dim3(256), 0, stream,
                       tr, lsp, bwp, ws, out_bands);
    hipLaunchKernelGGL(setup_b_kernel, dim3(40), dim3(256), 0, stream, ws);
    hipLaunchKernelGGL(cwt_main_kernel, dim3(8000), dim3(128), 0, stream,
                       ts, ws, out);
}